// Round 1
// baseline (2215.510 us; speedup 1.0000x reference)
//
#include <hip/hip_runtime.h>
#include <hip/hip_bf16.h>

// Problem constants (fixed by the reference): B=2048, T=256, D=512, H=10
#define BSZ 2048
#define TSZ 256
#define DSZ 512
#define HSZ 10
#define GSZ 30  // 3H

// ---------------------------------------------------------------------------
// Kernel 1: x_proj[t][g][b] = sum_d x[b][t][d] * W_ih[g][d] + b_ih[g]
// Layout [t][g][b] makes kernel-2 loads coalesced across b.
// Block = 256 threads, each thread owns one row (t, b0+tid).
// Grid = 2048 blocks: bx -> t = bx>>3, b0 = (bx&7)*256.
// x is staged through LDS so global reads are coalesced (8 lanes x 32 floats
// = one 128B line per 8 lanes); W_ih is read with wave-uniform indices so the
// compiler can scalarize to s_load (SGPR operand on v_fma, no LDS traffic).
// ---------------------------------------------------------------------------
__global__ __launch_bounds__(256, 4) void xproj_kernel(
    const float* __restrict__ x, const float* __restrict__ W,
    const float* __restrict__ b_ih, float* __restrict__ xp)
{
    const int tid = threadIdx.x;
    const int t  = blockIdx.x >> 3;
    const int b0 = (blockIdx.x & 7) << 8;

    // LDS tile: 256 rows x 32 floats, row stride padded to 36 floats (144 B,
    // 16B-aligned, bank-group stride 4 -> conflict-free at the b128 floor).
    __shared__ float xs[256 * 36];

    float acc[GSZ];
#pragma unroll
    for (int g = 0; g < GSZ; ++g) acc[g] = 0.f;

    for (int d0 = 0; d0 < DSZ; d0 += 32) {
        __syncthreads();  // previous tile fully consumed
        // stage 256 rows x 32 floats: flat float4 index = i*256+tid,
        // row r = flat>>3 (8 float4 per row), col c = flat&7
#pragma unroll
        for (int i = 0; i < 8; ++i) {
            int flat = i * 256 + tid;
            int r = flat >> 3;
            int c = flat & 7;
            const float4 v = *(const float4*)(
                x + ((size_t)(b0 + r) * TSZ + t) * DSZ + d0 + c * 4);
            *(float4*)&xs[r * 36 + c * 4] = v;
        }
        __syncthreads();

        const float* xr = &xs[tid * 36];
#pragma unroll
        for (int k = 0; k < 8; ++k) {
            float4 xv = *(const float4*)(xr + 4 * k);
            const float* wp = W + d0 + 4 * k;  // wave-uniform
#pragma unroll
            for (int g = 0; g < GSZ; ++g) {
                float4 wv = *(const float4*)(wp + (size_t)g * DSZ);
                acc[g] = fmaf(xv.x, wv.x,
                         fmaf(xv.y, wv.y,
                         fmaf(xv.z, wv.z,
                         fmaf(xv.w, wv.w, acc[g]))));
            }
        }
    }

    // epilogue: add b_ih, write transposed xp[t][g][b] (coalesced across tid)
    const int b = b0 + tid;
    float* op = xp + (size_t)t * GSZ * BSZ + b;
#pragma unroll
    for (int g = 0; g < GSZ; ++g) {
        op[(size_t)g * BSZ] = acc[g] + b_ih[g];
    }
}

// ---------------------------------------------------------------------------
// Kernel 2: the serial GRU recurrence over T=256 steps.
// Thread <-> (hidden unit j, batch b). Block = 320 threads = 10 j x 32 b.
// Grid = 64 blocks (2048/32). W_hh rows j, j+10, j+20 live in registers.
// h double-buffered in LDS (row stride 11 floats -> conflict-free),
// one __syncthreads per step.
// Only the last step's (r, z, n, h) are outputs; written twice (tuple of two
// reshapes of the same data).
// ---------------------------------------------------------------------------
__device__ __forceinline__ float sigmoid_f(float a) {
    return 1.0f / (1.0f + __expf(-a));
}
__device__ __forceinline__ float tanh_f(float a) {
    // tanh(a) = 2/(1+exp(-2a)) - 1 ; exact limits at +-inf
    return 2.0f / (1.0f + __expf(-2.0f * a)) - 1.0f;
}

__global__ __launch_bounds__(320, 2) void rnn_kernel(
    const float* __restrict__ xp, const float* __restrict__ h0,
    const float* __restrict__ Whh, const float* __restrict__ b_hh,
    float* __restrict__ out)
{
    const int tid = threadIdx.x;
    const int j  = tid >> 5;        // 0..9
    const int bl = tid & 31;        // 0..31
    const int b  = blockIdx.x * 32 + bl;

    // W_hh rows j, j+10, j+20 in registers (30 floats)
    float wr[HSZ], wz[HSZ], wn[HSZ];
#pragma unroll
    for (int k = 0; k < HSZ; ++k) {
        wr[k] = Whh[(j)      * HSZ + k];
        wz[k] = Whh[(j + 10) * HSZ + k];
        wn[k] = Whh[(j + 20) * HSZ + k];
    }
    const float bhr = b_hh[j], bhz = b_hh[j + 10], bhn = b_hh[j + 20];

    __shared__ float hbuf[2][32 * 11];
    hbuf[0][bl * 11 + j] = h0[(size_t)b * HSZ + j];
    __syncthreads();

    float rj = 0.f, zj = 0.f, nj = 0.f, hj = 0.f;
    int cur = 0;
    for (int t = 0; t < TSZ; ++t) {
        float hk[HSZ];
#pragma unroll
        for (int k = 0; k < HSZ; ++k) hk[k] = hbuf[cur][bl * 11 + k];

        float hr = bhr, hz = bhz, hn = bhn;
#pragma unroll
        for (int k = 0; k < HSZ; ++k) {
            hr = fmaf(wr[k], hk[k], hr);
            hz = fmaf(wz[k], hk[k], hz);
            hn = fmaf(wn[k], hk[k], hn);
        }

        const float* xpt = xp + (size_t)t * GSZ * BSZ + b;
        const float xr = xpt[(size_t)(j)      * BSZ];
        const float xz = xpt[(size_t)(j + 10) * BSZ];
        const float xn = xpt[(size_t)(j + 20) * BSZ];

        rj = sigmoid_f(xr + hr);
        zj = sigmoid_f(xz + hz);
        nj = tanh_f(xn + rj * hn);
        hj = (1.0f - zj) * nj + zj * hk[j];

        hbuf[cur ^ 1][bl * 11 + j] = hj;
        cur ^= 1;
        __syncthreads();
    }

    // outputs: full = concat([r, z, n, h], axis=1) -> (B, 40), duplicated
    const size_t o1 = (size_t)b * 40;
    out[o1 + j]            = rj;
    out[o1 + 10 + j]       = zj;
    out[o1 + 20 + j]       = nj;
    out[o1 + 30 + j]       = hj;
    const size_t o2 = o1 + (size_t)BSZ * 40;
    out[o2 + j]            = rj;
    out[o2 + 10 + j]       = zj;
    out[o2 + 20 + j]       = nj;
    out[o2 + 30 + j]       = hj;
}

// ---------------------------------------------------------------------------
extern "C" void kernel_launch(void* const* d_in, const int* in_sizes, int n_in,
                              void* d_out, int out_size, void* d_ws, size_t ws_size,
                              hipStream_t stream) {
    const float* x   = (const float*)d_in[0];
    const float* h0  = (const float*)d_in[1];
    const float* Wih = (const float*)d_in[2];
    const float* Whh = (const float*)d_in[3];
    const float* bih = (const float*)d_in[4];
    const float* bhh = (const float*)d_in[5];
    float* out = (float*)d_out;
    float* xp  = (float*)d_ws;  // 256*30*2048 floats = 62.9 MB

    xproj_kernel<<<dim3(2048), dim3(256), 0, stream>>>(x, Wih, bih, xp);
    rnn_kernel<<<dim3(64), dim3(320), 0, stream>>>(xp, h0, Whh, bhh, out);
}